// Round 1
// baseline (385.788 us; speedup 1.0000x reference)
//
#include <hip/hip_runtime.h>
#include <hip/hip_bf16.h>

// Reference constants
#define L_LEN   8192
#define SEG     512
#define NFEATS  256
#define SCALE_2PI 6.283185307179586f
#define EPS_REF 1e-6f

// log2(10000)/128 : inv_dim_t for pair k = exp2(-k * STEP)
#define STEP_LOG2 0.1038102529652301f

// ---------------- Phase 1: per-row segmented cumsum -> normalized x_embed ----
// One block per batch row. 256 threads, each owns a contiguous chunk of 32.
__global__ __launch_bounds__(256) void pe_phase1(const int* __restrict__ mask,
                                                 float* __restrict__ xe) {
    constexpr int THREADS = 256;
    constexpr int CHUNK = L_LEN / THREADS; // 32

    __shared__ int c[L_LEN];        // inclusive cumsum of mask (32 KB)
    __shared__ int partials[THREADS];
    __shared__ int firstIdx;

    const int t = threadIdx.x;
    const int b = blockIdx.x;
    const int* mrow = mask + (long)b * L_LEN;

    if (t == 0) firstIdx = L_LEN;
    __syncthreads();

    // Load this thread's chunk (vectorized int4)
    int m[CHUNK];
    const int base = t * CHUNK;
    const int4* mv = (const int4*)(mrow + base);
#pragma unroll
    for (int j = 0; j < CHUNK / 4; ++j) {
        int4 v = mv[j];
        m[4 * j + 0] = v.x; m[4 * j + 1] = v.y;
        m[4 * j + 2] = v.z; m[4 * j + 3] = v.w;
    }

    // chunk sum + local first-valid
    int s = 0;
    int lf = L_LEN;
#pragma unroll
    for (int j = 0; j < CHUNK; ++j) {
        if (m[j] != 0 && lf == L_LEN) lf = base + j;
        s += m[j];
    }
    partials[t] = s;
    if (lf < L_LEN) atomicMin(&firstIdx, lf);
    __syncthreads();

    // Hillis-Steele inclusive scan over 256 chunk sums
    for (int off = 1; off < THREADS; off <<= 1) {
        int v = partials[t];
        int add = (t >= off) ? partials[t - off] : 0;
        __syncthreads();
        partials[t] = v + add;
        __syncthreads();
    }

    // write inclusive cumsum for this chunk into LDS
    int run = partials[t] - s; // exclusive prefix of chunk
#pragma unroll
    for (int j = 0; j < CHUNK; ++j) {
        run += m[j];
        c[base + j] = run;
    }
    __syncthreads();

    const int start = firstIdx;
    const bool hv = (start < L_LEN);
    float* xrow = xe + (long)b * L_LEN;

#pragma unroll
    for (int j = 0; j < CHUNK; ++j) {
        const int i = base + j;
        float e = 0.0f;
        const int rel = i - start;
        if (hv && rel >= 0) {
            const int seg_start = start + (rel / SEG) * SEG;
            const int seg_end = min(seg_start + SEG, L_LEN);
            const int cprev = (seg_start > 0) ? c[seg_start - 1] : 0;
            const int ci = c[i];
            const int clast = c[seg_end - 1];
            e = (float)(ci - cprev) / ((float)(clast - cprev) + EPS_REF) * SCALE_2PI;
        }
        xrow[i] = e;
    }
}

// ---------------- Phase 2: expand to sin/cos features (HBM-write bound) -----
// One wave per position per iteration; lane l covers feature pairs 2l, 2l+1
// -> one float4 store per lane = 1 KB coalesced per wave store.
// Block = 256 threads (4 waves), each block covers 16 positions.
__global__ __launch_bounds__(256) void pe_phase2(const float* __restrict__ xe,
                                                 float4* __restrict__ out) {
    const int lane = threadIdx.x & 63;
    const int wave = threadIdx.x >> 6;

    // dim_t reciprocal, hoisted out of the position loop
    const float inv0 = exp2f(-(float)(2 * lane) * STEP_LOG2);
    const float inv1 = exp2f(-(float)(2 * lane + 1) * STEP_LOG2);

    const int p0 = blockIdx.x * 16 + wave * 4;
#pragma unroll
    for (int j = 0; j < 4; ++j) {
        const int p = p0 + j;
        const float e = xe[p];           // wave-broadcast load
        const float t0 = e * inv0;
        const float t1 = e * inv1;
        float s0, c0, s1, c1;
        __sincosf(t0, &s0, &c0);
        __sincosf(t1, &s1, &c1);
        out[(long)p * (NFEATS / 4) + lane] = make_float4(s0, c0, s1, c1);
    }
}

extern "C" void kernel_launch(void* const* d_in, const int* in_sizes, int n_in,
                              void* d_out, int out_size, void* d_ws, size_t ws_size,
                              hipStream_t stream) {
    // inputs: d_in[0] = x (unused), d_in[1] = mask (int32, B*L)
    const int* mask = (const int*)d_in[1];
    float* out = (float*)d_out;
    float* xe = (float*)d_ws;            // B*L floats = 1 MB scratch

    const int B = in_sizes[1] / L_LEN;   // 32
    const int npos = B * L_LEN;          // 262144

    pe_phase1<<<dim3(B), dim3(256), 0, stream>>>(mask, xe);
    pe_phase2<<<dim3(npos / 16), dim3(256), 0, stream>>>(xe, (float4*)out);
}